// Round 8
// baseline (293.919 us; speedup 1.0000x reference)
//
#include <hip/hip_runtime.h>
#include <stdint.h>
#include <math.h>

// Problem constants
#define MM 256          // B*S = 32*8
#define KD 1024         // D
#define K2 2048         // combined K (real|imag)
#define VV 50257        // vocab
#define NF4 (VV / 4)    // 12564 float4 slots; elem 50256 is the tail
#define NSTEP 32        // K2 / BK
#define NTILES 786      // ceil(VV / BN)

static constexpr size_t OUT_TOKENS = (size_t)MM * VV;            // 12865792
static constexpr size_t OUT_PROBS  = OUT_TOKENS + MM;            // 12866048
static constexpr size_t OUT_LOGPR  = OUT_PROBS + (size_t)MM * VV;// 25731840

// ws layout: [0, 2MB) packed A ; [2MB, +4KB) row stats ; [2MB+4KB] tile counter
#define WS_ABUF_BYTES (2u * 1024u * 1024u)
#define WS_CTR_OFF (WS_ABUF_BYTES + 4096u)

typedef __attribute__((ext_vector_type(8))) short bf16x8;
typedef __attribute__((ext_vector_type(4))) float f32x4;

// ---------------- bf16 split helpers --------------------------------------
__device__ __forceinline__ ushort f2bf(float x) {
  unsigned u = __float_as_uint(x);
  unsigned r = u + 0x7FFFu + ((u >> 16) & 1u);   // RNE
  return (ushort)(r >> 16);
}
__device__ __forceinline__ float bf2f(ushort h) {
  return __uint_as_float(((unsigned)h) << 16);
}

// ---------------- Threefry-2x32-20 (JAX-compatible) ----------------
__device__ __forceinline__ unsigned rotl32(unsigned x, int r) {
  return (x << r) | (x >> (32 - r));
}

__device__ __forceinline__ uint2 threefry2x32(unsigned k0, unsigned k1,
                                              unsigned x0, unsigned x1) {
  unsigned ks[3] = {k0, k1, k0 ^ k1 ^ 0x1BD11BDAu};
  const int rot[8] = {13, 15, 26, 6, 17, 29, 16, 24};
  x0 += ks[0]; x1 += ks[1];
  #pragma unroll
  for (int g = 0; g < 5; ++g) {
    const int base = (g & 1) ? 4 : 0;
    #pragma unroll
    for (int i = 0; i < 4; ++i) {
      x0 += x1;
      x1 = rotl32(x1, rot[base + i]);
      x1 ^= x0;
    }
    x0 += ks[(g + 1) % 3];
    x1 += ks[(g + 2) % 3] + (unsigned)(g + 1);
  }
  return make_uint2(x0, x1);
}

__device__ __forceinline__ float gumbel_at(unsigned flat) {
  uint2 r = threefry2x32(0u, 42u, 0u, flat);
  unsigned w = r.x ^ r.y;
  unsigned fb = (w >> 9) | 0x3F800000u;
  float f = __uint_as_float(fb) - 1.0f;
  const float tiny = 1.1754943508222875e-38f;
  float u = fmaxf(tiny, f + tiny);
  float t1 = (float)log((double)u);
  float t3 = (float)log((double)(-t1));
  return -t3;
}

// ---------------- K0: pack psi -> hi/lo bf16 in MFMA fragment layout ------
__global__ __launch_bounds__(256)
void k_prep(const float* __restrict__ psi_r, const float* __restrict__ psi_i,
            ushort* __restrict__ a_buf) {
  int t = blockIdx.x * 256 + threadIdx.x;   // 65536 threads: (s, mb, lane)
  int lane = t & 63;
  int mb = (t >> 6) & 15;
  int s = t >> 10;                          // 0..63
  int lr = lane & 15, lg = lane >> 4;
  int m = mb * 16 + lr;
  int kloc = (s & 31) * 32 + lg * 8;
  const float* __restrict__ src = (s < 32) ? psi_r : psi_i;
  float4 v0 = *reinterpret_cast<const float4*>(&src[m * KD + kloc]);
  float4 v1 = *reinterpret_cast<const float4*>(&src[m * KD + kloc + 4]);
  float in[8] = {v0.x, v0.y, v0.z, v0.w, v1.x, v1.y, v1.z, v1.w};
  ushort h[8], l[8];
  #pragma unroll
  for (int j = 0; j < 8; ++j) {
    h[j] = f2bf(in[j]);
    l[j] = f2bf(in[j] - bf2f(h[j]));
  }
  size_t base = ((size_t)(s * 16 + mb) * 2) * 512 + (size_t)lane * 8;
  #pragma unroll
  for (int j = 0; j < 8; ++j) {
    a_buf[base + j] = h[j];
    a_buf[base + 512 + j] = l[j];
  }
}

// ---------------- K1: persistent dynamic-tile split-bf16 MFMA GEMM --------
#define BN 64
#define BK 64
#define GT 256

struct W4 { float4 a, b, c, d; };
struct A8 { uint4 h[4]; uint4 l[4]; };

__device__ __forceinline__ void loadW(W4& w, const float* __restrict__ Wr,
                                      const float* __restrict__ Wi,
                                      int t, int gn, int bcol) {
  const float* __restrict__ Bs = (t < 16) ? Wr : Wi;
  int ko = (t << 6) & (KD - 1);
  if (gn < VV) {
    const float* p = &Bs[(size_t)gn * KD + ko + bcol];
    w.a = *reinterpret_cast<const float4*>(p);
    w.b = *reinterpret_cast<const float4*>(p + 4);
    w.c = *reinterpret_cast<const float4*>(p + 8);
    w.d = *reinterpret_cast<const float4*>(p + 12);
  }
}

__device__ __forceinline__ void stageW(const W4& w, ushort* __restrict__ bh,
                                       ushort* __restrict__ bl, int eo0, int eo1) {
  float in[16] = {w.a.x, w.a.y, w.a.z, w.a.w, w.b.x, w.b.y, w.b.z, w.b.w,
                  w.c.x, w.c.y, w.c.z, w.c.w, w.d.x, w.d.y, w.d.z, w.d.w};
  ushort h[16], l[16];
  #pragma unroll
  for (int j = 0; j < 16; ++j) {
    h[j] = f2bf(in[j]);
    l[j] = f2bf(in[j] - bf2f(h[j]));
  }
  *reinterpret_cast<uint4*>(&bh[eo0]) =
      make_uint4((unsigned)h[0] | ((unsigned)h[1] << 16),
                 (unsigned)h[2] | ((unsigned)h[3] << 16),
                 (unsigned)h[4] | ((unsigned)h[5] << 16),
                 (unsigned)h[6] | ((unsigned)h[7] << 16));
  *reinterpret_cast<uint4*>(&bh[eo1]) =
      make_uint4((unsigned)h[8] | ((unsigned)h[9] << 16),
                 (unsigned)h[10] | ((unsigned)h[11] << 16),
                 (unsigned)h[12] | ((unsigned)h[13] << 16),
                 (unsigned)h[14] | ((unsigned)h[15] << 16));
  *reinterpret_cast<uint4*>(&bl[eo0]) =
      make_uint4((unsigned)l[0] | ((unsigned)l[1] << 16),
                 (unsigned)l[2] | ((unsigned)l[3] << 16),
                 (unsigned)l[4] | ((unsigned)l[5] << 16),
                 (unsigned)l[6] | ((unsigned)l[7] << 16));
  *reinterpret_cast<uint4*>(&bl[eo1]) =
      make_uint4((unsigned)l[8] | ((unsigned)l[9] << 16),
                 (unsigned)l[10] | ((unsigned)l[11] << 16),
                 (unsigned)l[12] | ((unsigned)l[13] << 16),
                 (unsigned)l[14] | ((unsigned)l[15] << 16));
}

__device__ __forceinline__ void loadA(A8& A, const uint4* __restrict__ a_buf,
                                      int s, int kq, int wid, int lane) {
  #pragma unroll
  for (int mi = 0; mi < 4; ++mi) {
    int chunk2 = (((s * 2 + kq) * 16) + wid * 4 + mi) * 2;
    A.h[mi] = a_buf[(size_t)chunk2 * 64 + lane];
    A.l[mi] = a_buf[(size_t)(chunk2 + 1) * 64 + lane];
  }
}

__device__ __forceinline__ void computeKQ(f32x4 (&acc)[4][4], const A8& A,
                                          const ushort* __restrict__ bhp,
                                          const ushort* __restrict__ blp,
                                          int kq, int lr, int lg) {
  bf16x8 bh[4], bl[4];
  #pragma unroll
  for (int ni = 0; ni < 4; ++ni) {
    int r = ni * 16 + lr;
    int eoff = r * BK + ((kq * 32 + lg * 8) ^ ((r & 7) << 3));
    bh[ni] = *reinterpret_cast<const bf16x8*>(&bhp[eoff]);
    bl[ni] = *reinterpret_cast<const bf16x8*>(&blp[eoff]);
  }
  __builtin_amdgcn_s_setprio(1);
  #pragma unroll
  for (int mi = 0; mi < 4; ++mi) {
    bf16x8 ah = *reinterpret_cast<const bf16x8*>(&A.h[mi]);
    bf16x8 al = *reinterpret_cast<const bf16x8*>(&A.l[mi]);
    #pragma unroll
    for (int ni = 0; ni < 4; ++ni) {
      acc[mi][ni] = __builtin_amdgcn_mfma_f32_16x16x32_bf16(ah, bh[ni], acc[mi][ni], 0, 0, 0);
      acc[mi][ni] = __builtin_amdgcn_mfma_f32_16x16x32_bf16(al, bh[ni], acc[mi][ni], 0, 0, 0);
      acc[mi][ni] = __builtin_amdgcn_mfma_f32_16x16x32_bf16(ah, bl[ni], acc[mi][ni], 0, 0, 0);
    }
  }
  __builtin_amdgcn_s_setprio(0);
}

__global__ __launch_bounds__(GT, 2)
void k_gemm(const uint4* __restrict__ a_buf,
            const float* __restrict__ Wr, const float* __restrict__ Wi,
            const float* __restrict__ bias, float* __restrict__ logits,
            unsigned* __restrict__ tile_ctr) {
  __shared__ ushort sBh[2][BN * BK];   // 8 KB per buf
  __shared__ ushort sBl[2][BN * BK];
  __shared__ int s_tile;

  const int tid  = threadIdx.x;
  const int lane = tid & 63;
  const int wid  = tid >> 6;    // 0..3 -> m block of 64
  const int lr = lane & 15;
  const int lg = lane >> 4;

  // B staging coords: 4 threads per row, 16 f32 per thread
  const int brow = tid >> 2;          // 0..63
  const int bcol = (tid & 3) << 4;    // 0,16,32,48
  const int eo0  = brow * BK + (bcol ^ ((brow & 7) << 3));
  const int eo1  = brow * BK + ((bcol + 8) ^ ((brow & 7) << 3));

  for (;;) {
    if (tid == 0) s_tile = (int)atomicAdd(tile_ctr, 1u);
    __syncthreads();
    const int tile = s_tile;
    __syncthreads();             // protect s_tile before next grab
    if (tile >= NTILES) break;

    const int vb = tile * BN;
    const int gn = vb + brow;

    f32x4 acc[4][4];
    #pragma unroll
    for (int i = 0; i < 4; ++i)
      #pragma unroll
      for (int j = 0; j < 4; ++j)
        #pragma unroll
        for (int q = 0; q < 4; ++q) acc[i][j][q] = 0.f;

    // ---- prologue: W[0]->wX->buf0 ; W[1]->wY ; W[2]->wX ; A(0,0)
    W4 wX, wY;
    wX.a = wX.b = wX.c = wX.d = make_float4(0.f, 0.f, 0.f, 0.f);
    wY = wX;
    A8 A0, A1;
    loadW(wX, Wr, Wi, 0, gn, bcol);
    loadW(wY, Wr, Wi, 1, gn, bcol);
    loadA(A0, a_buf, 0, 0, wid, lane);
    stageW(wX, &sBh[0][0], &sBl[0][0], eo0, eo1);
    loadW(wX, Wr, Wi, 2, gn, bcol);
    asm volatile("s_waitcnt lgkmcnt(0)" ::: "memory");
    asm volatile("s_barrier" ::: "memory");

    for (int sp = 0; sp < NSTEP / 2; ++sp) {
      const int s0 = sp * 2;
      const int s1 = s0 + 1;
      // ---- step s0: read buf[0], stage W[s0+1] from wY -> buf[1]
      loadA(A1, a_buf, s0, 1, wid, lane);
      stageW(wY, &sBh[1][0], &sBl[1][0], eo0, eo1);
      if (s0 + 3 < NSTEP) loadW(wY, Wr, Wi, s0 + 3, gn, bcol);
      computeKQ(acc, A0, &sBh[0][0], &sBl[0][0], 0, lr, lg);
      loadA(A0, a_buf, s1, 0, wid, lane);
      computeKQ(acc, A1, &sBh[0][0], &sBl[0][0], 1, lr, lg);
      asm volatile("s_waitcnt lgkmcnt(0)" ::: "memory");
      asm volatile("s_barrier" ::: "memory");
      // ---- step s1: read buf[1], stage W[s1+1] from wX -> buf[0]
      loadA(A1, a_buf, s1, 1, wid, lane);
      if (s1 + 1 < NSTEP) stageW(wX, &sBh[0][0], &sBl[0][0], eo0, eo1);
      if (s1 + 3 < NSTEP) loadW(wX, Wr, Wi, s1 + 3, gn, bcol);
      computeKQ(acc, A0, &sBh[1][0], &sBl[1][0], 0, lr, lg);
      if (s1 < NSTEP - 1) loadA(A0, a_buf, s1 + 1, 0, wid, lane);
      computeKQ(acc, A1, &sBh[1][0], &sBl[1][0], 1, lr, lg);
      asm volatile("s_waitcnt lgkmcnt(0)" ::: "memory");
      asm volatile("s_barrier" ::: "memory");
    }

    // epilogue: D layout col=lane&15, row=(lane>>4)*4+reg
    #pragma unroll
    for (int ni = 0; ni < 4; ++ni) {
      int n = vb + ni * 16 + lr;
      if (n < VV) {
        float b = bias[n];
        #pragma unroll
        for (int mi = 0; mi < 4; ++mi) {
          #pragma unroll
          for (int j = 0; j < 4; ++j) {
            int m = wid * 64 + mi * 16 + lg * 4 + j;
            logits[(size_t)m * VV + n] = acc[mi][ni][j] + b;
          }
        }
      }
    }
    __syncthreads();   // all waves done with LDS before next tile's staging
  }
}

// ---------------- K2: fused row stats (max, lse) + top-50 threshold -------
__device__ __forceinline__ unsigned ordf(float f) {
  unsigned u = __float_as_uint(f);
  return u ^ ((u >> 31) ? 0xFFFFFFFFu : 0x80000000u);
}

#define HREP 4
#define HSTRIDE 4097

__global__ __launch_bounds__(1024)
void k_stats(const float* __restrict__ logits, float* __restrict__ ws4) {
  const int row = blockIdx.x;
  const int tid = threadIdx.x;
  const float* __restrict__ x = logits + (size_t)row * VV;

  __shared__ unsigned hist[HREP * HSTRIDE];   // 64 KB + eps
  __shared__ float pm[16], ps[16];

  for (int i = tid; i < HREP * HSTRIDE; i += 1024) hist[i] = 0u;
  __syncthreads();

  const int rep = (tid & 3) * HSTRIDE;
  float lm = -INFINITY, ls = 0.f;
  for (int i4 = tid; i4 < NF4; i4 += 1024) {
    float4 v4 = *reinterpret_cast<const float4*>(&x[i4 * 4]);
    float vs[4] = {v4.x, v4.y, v4.z, v4.w};
    #pragma unroll
    for (int j = 0; j < 4; ++j) {
      float v = vs[j];
      atomicAdd(&hist[rep + (ordf(v) >> 20)], 1u);
      if (v <= lm) {
        ls += expf(v - lm);
      } else {
        ls = ls * expf(lm - v) + 1.f;
        lm = v;
      }
    }
  }
  if (tid == 0) {   // tail element
    float v = x[VV - 1];
    atomicAdd(&hist[ordf(v) >> 20], 1u);
    if (v <= lm) ls += expf(v - lm);
    else { ls = ls * expf(lm - v) + 1.f; lm = v; }
  }
  // wave-level (m,s) reduce
  #pragma unroll
  for (int off = 32; off; off >>= 1) {
    float om = __shfl_xor(lm, off);
    float os = __shfl_xor(ls, off);
    float M = fmaxf(lm, om);
    ls = ls * expf(lm - M) + os * expf(om - M);
    lm = M;
  }
  if ((tid & 63) == 0) { pm[tid >> 6] = lm; ps[tid >> 6] = ls; }
  __syncthreads();

  // merge histogram replicas into replica 0
  for (int b = tid; b < 4096; b += 1024)
    hist[b] = hist[b] + hist[HSTRIDE + b] + hist[2 * HSTRIDE + b] + hist[3 * HSTRIDE + b];
  __syncthreads();

  if (tid < 64) {
    // merge 16 wave partials (lanes >=16 use finite identity to avoid NaN)
    float m2 = (tid < 16) ? pm[tid] : -3e38f;
    float s2 = (tid < 16) ? ps[tid] : 0.f;
    #pragma unroll
    for (int off = 8; off; off >>= 1) {
      float om = __shfl_xor(m2, off);
      float os = __shfl_xor(s2, off);
      float M = fmaxf(m2, om);
      s2 = s2 * expf(m2 - M) + os * expf(om - M);
      m2 = M;
    }
    // segment sums of hist: lane l owns bins [l*64, l*64+64) (rotated reads)
    unsigned seg = 0;
    #pragma unroll 8
    for (int b = 0; b < 64; ++b) seg += hist[tid * 64 + ((b + tid) & 63)];
    // suffix scan: suf[l] = sum_{j>=l} seg[j]
    unsigned suf = seg;
    #pragma unroll
    for (int off = 1; off < 64; off <<= 1) {
      unsigned o = __shfl_down(suf, off);
      if (tid + off < 64) suf += o;
    }
    unsigned long long mk = __ballot(suf >= 50u);
    int lstar = 63 - __builtin_clzll(mk);       // highest segment with suffix>=50
    unsigned above = (lstar < 63) ? (unsigned)__shfl((int)suf, lstar + 1) : 0u;
    if (tid == 0) {
      unsigned cum = above;
      int bin = lstar * 64;
      for (int b = 63; b >= 0; --b) {
        cum += hist[lstar * 64 + b];
        if (cum >= 50u) { bin = lstar * 64 + b; break; }
      }
      ws4[row * 4 + 0] = m2;
      ws4[row * 4 + 1] = logf(s2);
      ws4[row * 4 + 2] = __uint_as_float((unsigned)bin << 20);
    }
  }
}

// ---------------- K3: fused log_probs + probs-zero + collect + sample -----
#define CAP 1024

__global__ __launch_bounds__(1024)
void k_post(const float* __restrict__ logits, const float* __restrict__ ws4,
            float* __restrict__ logpr, float* __restrict__ probs,
            float* __restrict__ tokens) {
  const int row = blockIdx.x;
  const int tid = threadIdx.x;
  const float* __restrict__ x = logits + (size_t)row * VV;
  float* __restrict__ lp = logpr + (size_t)row * VV;
  float* __restrict__ pr = probs + (size_t)row * VV;

  __shared__ float cv[CAP];
  __shared__ int   ci[CAP];
  __shared__ unsigned s_cnt;
  __shared__ float top_v[50];
  __shared__ int   top_i[50];

  if (tid == 0) s_cnt = 0u;
  __syncthreads();

  const float mx = ws4[row * 4 + 0];
  const float lz = ws4[row * 4 + 1];
  const unsigned lo = __float_as_uint(ws4[row * 4 + 2]);
  const float4 z4 = make_float4(0.f, 0.f, 0.f, 0.f);

  for (int i4 = tid; i4 < NF4; i4 += 1024) {
    float4 v = *reinterpret_cast<const float4*>(&x[i4 * 4]);
    *reinterpret_cast<float4*>(&lp[i4 * 4]) =
        make_float4((v.x - mx) - lz, (v.y - mx) - lz,
                    (v.z - mx) - lz, (v.w - mx) - lz);
    *reinterpret_cast<float4*>(&pr[i4 * 4]) = z4;
    float vs[4] = {v.x, v.y, v.z, v.w};
    #pragma unroll
    for (int j = 0; j < 4; ++j) {
      if (ordf(vs[j]) >= lo) {
        unsigned pos = atomicAdd(&s_cnt, 1u);
        if (pos < CAP) { cv[pos] = vs[j]; ci[pos] = i4 * 4 + j; }
      }
    }
  }
  if (tid == 0) {
    float v = x[VV - 1];
    lp[VV - 1] = (v - mx) - lz;
    pr[VV - 1] = 0.f;
    if (ordf(v) >= lo) {
      unsigned pos = atomicAdd(&s_cnt, 1u);
      if (pos < CAP) { cv[pos] = v; ci[pos] = VV - 1; }
    }
  }
  __syncthreads();
  const int ncand = (int)min(s_cnt, (unsigned)CAP);

  if (tid < 64) {
    // 50-round wave argmax (value desc, index asc)
    for (int it = 0; it < 50; ++it) {
      float bv = -INFINITY;
      int bi = 0x7FFFFFFF, bs = 0;
      for (int c = tid; c < ncand; c += 64) {
        float v = cv[c];
        int id = ci[c];
        if (v > bv || (v == bv && id < bi)) { bv = v; bi = id; bs = c; }
      }
      #pragma unroll
      for (int off = 32; off; off >>= 1) {
        float ov = __shfl_xor(bv, off);
        int oi = __shfl_xor(bi, off);
        int os = __shfl_xor(bs, off);
        if (ov > bv || (ov == bv && oi < bi)) { bv = ov; bi = oi; bs = os; }
      }
      if (tid == 0) {
        top_v[it] = bv;
        top_i[it] = bi;
        cv[bs] = -INFINITY;   // same-wave LDS ops in-order
      }
    }

    // lane-parallel softmax / top-p / gumbel over the 50 survivors
    float tv = (tid < 50) ? top_v[tid] : -3e38f;
    float m0 = top_v[0];
    float sp = (tid < 50) ? expf(tv - m0) : 0.f;
    float Z = sp;
    #pragma unroll
    for (int off = 32; off; off >>= 1) Z += __shfl_xor(Z, off);
    float pref = sp;   // inclusive prefix over lane order
    #pragma unroll
    for (int off = 1; off < 64; off <<= 1) {
      float o = __shfl_up(pref, off);
      if (tid >= off) pref += o;
    }
    float excl = (pref - sp) / Z;
    bool keep = (tid < 50) && ((tid == 0) || (excl < 0.95f));
    float spk = keep ? sp : 0.f;
    float Z2 = spk;
    #pragma unroll
    for (int off = 32; off; off >>= 1) Z2 += __shfl_xor(Z2, off);

    float bt = -3e38f;
    int bidx = 0x7FFFFFFF;
    if (keep) {
      int idx = top_i[tid];
      pr[idx] = sp / Z2;
      bt = tv + gumbel_at((unsigned)((size_t)row * VV + idx));
      bidx = idx;
    }
    #pragma unroll
    for (int off = 32; off; off >>= 1) {
      float ot = __shfl_xor(bt, off);
      int oi = __shfl_xor(bidx, off);
      if (ot > bt || (ot == bt && oi < bidx)) { bt = ot; bidx = oi; }
    }
    if (tid == 0) tokens[row] = (float)bidx;
  }
}

// ---------------- launch --------------------------------------------------
extern "C" void kernel_launch(void* const* d_in, const int* in_sizes, int n_in,
                              void* d_out, int out_size, void* d_ws, size_t ws_size,
                              hipStream_t stream) {
  const float* psi_r = (const float*)d_in[0];
  const float* psi_i = (const float*)d_in[1];
  const float* Wr    = (const float*)d_in[2];
  const float* Wi    = (const float*)d_in[3];
  const float* bias  = (const float*)d_in[4];
  float* out = (float*)d_out;

  ushort* a_buf = (ushort*)d_ws;
  float* ws4    = (float*)((char*)d_ws + WS_ABUF_BYTES);
  unsigned* ctr = (unsigned*)((char*)d_ws + WS_CTR_OFF);

  float* logits = out;
  float* tokens = out + OUT_TOKENS;
  float* probs  = out + OUT_PROBS;
  float* logpr  = out + OUT_LOGPR;

  hipMemsetAsync(ctr, 0, sizeof(unsigned), stream);
  k_prep<<<256, 256, 0, stream>>>(psi_r, psi_i, a_buf);
  k_gemm<<<1024, GT, 0, stream>>>((const uint4*)a_buf, Wr, Wi, bias, logits, ctr);
  k_stats<<<MM, 1024, 0, stream>>>(logits, ws4);
  k_post<<<MM, 1024, 0, stream>>>(logits, ws4, logpr, probs, tokens);
}